// Round 1
// baseline (2717.320 us; speedup 1.0000x reference)
//
#include <hip/hip_runtime.h>
#include <hip/hip_bf16.h>

typedef __hip_bfloat16 bf16;

#define NTOK   49
#define CDIM   256
#define NHEADS 8
#define HDIM   32
#define NWIN   64
#define BWIN   4096
#define MROWS  (BWIN * NTOK)      // 200704
#define QKVC   768
#define SCALE  0.17677669529663687f

// ---------------------------------------------------------------------------
// Kernel 1: qkv = x @ qkv_w^T + qkv_b   (fp32 compute, bf16 store)
// Output layout in ws: [b][which(3)][h(8)][n(49)][d(32)]  (bf16)
// ---------------------------------------------------------------------------
__global__ __launch_bounds__(256) void qkv_gemm_k(
    const float* __restrict__ x, const float* __restrict__ w,
    const float* __restrict__ bias, bf16* __restrict__ qkv)
{
    __shared__ float As[16][132];
    __shared__ float Bs[16][132];
    const int rowBase = blockIdx.x * 128;
    const int colBase = blockIdx.y * 128;
    const int tid = threadIdx.x;
    const int tx = tid & 15, ty = tid >> 4;
    const int lm = tid >> 1;          // 0..127
    const int lk = (tid & 1) * 8;     // 0 or 8

    float acc[8][8];
#pragma unroll
    for (int i = 0; i < 8; ++i)
#pragma unroll
        for (int j = 0; j < 8; ++j) acc[i][j] = 0.f;

    for (int k0 = 0; k0 < CDIM; k0 += 16) {
        float4 a0 = *(const float4*)(x + (size_t)(rowBase + lm) * CDIM + k0 + lk);
        float4 a1 = *(const float4*)(x + (size_t)(rowBase + lm) * CDIM + k0 + lk + 4);
        float4 b0 = *(const float4*)(w + (size_t)(colBase + lm) * CDIM + k0 + lk);
        float4 b1 = *(const float4*)(w + (size_t)(colBase + lm) * CDIM + k0 + lk + 4);
        As[lk+0][lm]=a0.x; As[lk+1][lm]=a0.y; As[lk+2][lm]=a0.z; As[lk+3][lm]=a0.w;
        As[lk+4][lm]=a1.x; As[lk+5][lm]=a1.y; As[lk+6][lm]=a1.z; As[lk+7][lm]=a1.w;
        Bs[lk+0][lm]=b0.x; Bs[lk+1][lm]=b0.y; Bs[lk+2][lm]=b0.z; Bs[lk+3][lm]=b0.w;
        Bs[lk+4][lm]=b1.x; Bs[lk+5][lm]=b1.y; Bs[lk+6][lm]=b1.z; Bs[lk+7][lm]=b1.w;
        __syncthreads();
#pragma unroll
        for (int kk = 0; kk < 16; ++kk) {
            float4 av0 = *(const float4*)&As[kk][ty*8];
            float4 av1 = *(const float4*)&As[kk][ty*8+4];
            float4 bv0 = *(const float4*)&Bs[kk][tx*8];
            float4 bv1 = *(const float4*)&Bs[kk][tx*8+4];
            float a[8] = {av0.x,av0.y,av0.z,av0.w,av1.x,av1.y,av1.z,av1.w};
            float b[8] = {bv0.x,bv0.y,bv0.z,bv0.w,bv1.x,bv1.y,bv1.z,bv1.w};
#pragma unroll
            for (int i = 0; i < 8; ++i)
#pragma unroll
                for (int j = 0; j < 8; ++j) acc[i][j] += a[i] * b[j];
        }
        __syncthreads();
    }

#pragma unroll
    for (int i = 0; i < 8; ++i) {
        int m = rowBase + ty*8 + i;
        int bw = m / NTOK;
        int n  = m - bw * NTOK;
#pragma unroll
        for (int j = 0; j < 8; ++j) {
            int c = colBase + tx*8 + j;
            float v = acc[i][j] + bias[c];
            int which = c >> 8, hh = (c >> 5) & 7, dd = c & 31;
            qkv[(size_t)(bw*24 + which*8 + hh) * (NTOK*HDIM) + n*HDIM + dd] =
                __float2bfloat16(v);
        }
    }
}

// ---------------------------------------------------------------------------
// Kernel 2: per (window b, head h): S = q k^T * scale + bias + mask,
//           P = softmax(S) -> attn out; O = P v -> ws (bf16, [b][n][c])
// ---------------------------------------------------------------------------
__global__ __launch_bounds__(256) void attn_k(
    const bf16* __restrict__ qkv, const float* __restrict__ mask,
    const float* __restrict__ bt, float* __restrict__ attn_out,
    bf16* __restrict__ o_ws)
{
    const int b = blockIdx.x;
    const int h = blockIdx.y;
    const int tid = threadIdx.x;
    const int wv = tid >> 6, ln = tid & 63;

    __shared__ float qs[NTOK * 33];
    __shared__ float ks[NTOK * 33];
    __shared__ float vs[NTOK * 33];
    __shared__ float ps[NTOK * 50];

    const bf16* qp = qkv + (size_t)(b*24 + h)      * (NTOK*HDIM);
    const bf16* kp = qkv + (size_t)(b*24 + 8 + h)  * (NTOK*HDIM);
    const bf16* vp = qkv + (size_t)(b*24 + 16 + h) * (NTOK*HDIM);

    for (int e = tid; e < NTOK*HDIM; e += 256) {
        int n = e >> 5, d = e & 31;
        qs[n*33+d] = (float)qp[e];
        ks[n*33+d] = (float)kp[e];
        vs[n*33+d] = (float)vp[e];
    }
    __syncthreads();

    const float* mrow = mask + (size_t)(b & (NWIN-1)) * (NTOK*NTOK);
    float* aout = attn_out + (((size_t)b * NHEADS + h) * NTOK) * NTOK;

    for (int i = wv; i < NTOK; i += 4) {
        float s = -1e30f;
        if (ln < NTOK) {
            int j = ln;
            float acc = 0.f;
#pragma unroll
            for (int d = 0; d < HDIM; ++d) acc += qs[i*33+d] * ks[j*33+d];
            int ih = i / 7, iw = i - ih*7;
            int jh = j / 7, jw = j - jh*7;
            float bias = bt[((ih - jh + 6)*13 + (iw - jw + 6)) * NHEADS + h];
            s = acc * SCALE + bias + mrow[i*NTOK + j];
        }
        float mx = s;
#pragma unroll
        for (int off = 32; off; off >>= 1) mx = fmaxf(mx, __shfl_xor(mx, off));
        float ev = (ln < NTOK) ? __expf(s - mx) : 0.f;
        float sum = ev;
#pragma unroll
        for (int off = 32; off; off >>= 1) sum += __shfl_xor(sum, off);
        float p = ev / sum;
        if (ln < NTOK) {
            ps[i*50 + ln] = p;
            aout[(size_t)i * NTOK + ln] = p;
        }
    }
    __syncthreads();

    // O[i][d] = sum_j P[i][j] * v[j][d]; lane = (row-pair select, d)
    for (int i0 = wv*2; i0 < NTOK; i0 += 8) {
        int i = i0 + (ln >> 5);
        int d = ln & 31;
        if (i < NTOK) {
            float acc = 0.f;
            for (int j = 0; j < NTOK; ++j) acc += ps[i*50+j] * vs[j*33+d];
            o_ws[((size_t)b*NTOK + i) * CDIM + h*HDIM + d] = __float2bfloat16(acc);
        }
    }
}

// ---------------------------------------------------------------------------
// Kernel 3: out = O @ proj_w^T + proj_b   (A bf16 from ws, fp32 compute)
// ---------------------------------------------------------------------------
__global__ __launch_bounds__(256) void proj_gemm_k(
    const bf16* __restrict__ A, const float* __restrict__ w,
    const float* __restrict__ bias, float* __restrict__ out)
{
    __shared__ float As[16][132];
    __shared__ float Bs[16][132];
    const int rowBase = blockIdx.x * 128;
    const int colBase = blockIdx.y * 128;
    const int tid = threadIdx.x;
    const int tx = tid & 15, ty = tid >> 4;
    const int lm = tid >> 1;
    const int lk = (tid & 1) * 8;

    float acc[8][8];
#pragma unroll
    for (int i = 0; i < 8; ++i)
#pragma unroll
        for (int j = 0; j < 8; ++j) acc[i][j] = 0.f;

    for (int k0 = 0; k0 < CDIM; k0 += 16) {
        // 8 bf16 = 16 bytes
        float4 araw = *(const float4*)(A + (size_t)(rowBase + lm) * CDIM + k0 + lk);
        const bf16* ah = (const bf16*)&araw;
        float4 b0 = *(const float4*)(w + (size_t)(colBase + lm) * CDIM + k0 + lk);
        float4 b1 = *(const float4*)(w + (size_t)(colBase + lm) * CDIM + k0 + lk + 4);
#pragma unroll
        for (int j = 0; j < 8; ++j) As[lk+j][lm] = (float)ah[j];
        Bs[lk+0][lm]=b0.x; Bs[lk+1][lm]=b0.y; Bs[lk+2][lm]=b0.z; Bs[lk+3][lm]=b0.w;
        Bs[lk+4][lm]=b1.x; Bs[lk+5][lm]=b1.y; Bs[lk+6][lm]=b1.z; Bs[lk+7][lm]=b1.w;
        __syncthreads();
#pragma unroll
        for (int kk = 0; kk < 16; ++kk) {
            float4 av0 = *(const float4*)&As[kk][ty*8];
            float4 av1 = *(const float4*)&As[kk][ty*8+4];
            float4 bv0 = *(const float4*)&Bs[kk][tx*8];
            float4 bv1 = *(const float4*)&Bs[kk][tx*8+4];
            float a[8] = {av0.x,av0.y,av0.z,av0.w,av1.x,av1.y,av1.z,av1.w};
            float b[8] = {bv0.x,bv0.y,bv0.z,bv0.w,bv1.x,bv1.y,bv1.z,bv1.w};
#pragma unroll
            for (int i = 0; i < 8; ++i)
#pragma unroll
                for (int j = 0; j < 8; ++j) acc[i][j] += a[i] * b[j];
        }
        __syncthreads();
    }

#pragma unroll
    for (int i = 0; i < 8; ++i) {
        int m = rowBase + ty*8 + i;
        float4 o0, o1;
        int c = colBase + tx*8;
        o0.x = acc[i][0] + bias[c+0]; o0.y = acc[i][1] + bias[c+1];
        o0.z = acc[i][2] + bias[c+2]; o0.w = acc[i][3] + bias[c+3];
        o1.x = acc[i][4] + bias[c+4]; o1.y = acc[i][5] + bias[c+5];
        o1.z = acc[i][6] + bias[c+6]; o1.w = acc[i][7] + bias[c+7];
        *(float4*)(out + (size_t)m * CDIM + c)     = o0;
        *(float4*)(out + (size_t)m * CDIM + c + 4) = o1;
    }
}

// ---------------------------------------------------------------------------
extern "C" void kernel_launch(void* const* d_in, const int* in_sizes, int n_in,
                              void* d_out, int out_size, void* d_ws, size_t ws_size,
                              hipStream_t stream)
{
    const float* x      = (const float*)d_in[0];   // [4096,49,256]
    const float* mask   = (const float*)d_in[1];   // [64,49,49]
    const float* qkv_w  = (const float*)d_in[2];   // [768,256]
    const float* qkv_b  = (const float*)d_in[3];   // [768]
    const float* proj_w = (const float*)d_in[4];   // [256,256]
    const float* proj_b = (const float*)d_in[5];   // [256]
    const float* bt     = (const float*)d_in[6];   // [169,8]

    float* out      = (float*)d_out;                       // [4096,49,256]
    float* attn_out = out + (size_t)MROWS * CDIM;          // [4096,8,49,49]

    bf16* qkv_ws = (bf16*)d_ws;                            // 154,140,672 elems
    bf16* o_ws   = qkv_ws + (size_t)MROWS * QKVC;          // 51,380,224 elems

    // Kernel 1: QKV projection. grid (200704/128, 768/128)
    qkv_gemm_k<<<dim3(MROWS/128, QKVC/128), 256, 0, stream>>>(x, qkv_w, qkv_b, qkv_ws);

    // Kernel 2: attention per (window, head)
    attn_k<<<dim3(BWIN, NHEADS), 256, 0, stream>>>(qkv_ws, mask, bt, attn_out, o_ws);

    // Kernel 3: output projection. grid (200704/128, 256/128)
    proj_gemm_k<<<dim3(MROWS/128, CDIM/128), 256, 0, stream>>>(o_ws, proj_w, proj_b, out);
}